// Round 5
// baseline (166.306 us; speedup 1.0000x reference)
//
#include <hip/hip_runtime.h>
#include <math.h>

// SoftCodebook fused kernel v5 for MI355X (gfx950).
// p = softmax( (h/||h||) @ (proto/||proto||)^T / 0.1 ),  z = p @ proto
// v5 = v4 with the k_prep offset bug fixed: cbZ starts at img+32768 HALVES
// (64 KiB), not img+16384 (v3/v4 wrote cbZ over the top half of cbS, which
// corrupted sim logits for d>=128 -> p error ~0.1).
// Structure: both B-images LDS-resident (64K cbS via global_load_lds to
// <64KiB offsets, 64K cbZ via global_load_dwordx4 + ds_write_b128), ONE
// barrier, then 8 waves run the full 16-row pipeline independently with a
// wave-private LDS p-transpose buffer. LDS = 163840 B -> 1 block/CU.

#define EPS 1e-12f
#define TAU_INV 10.0f

typedef _Float16 f16x8 __attribute__((ext_vector_type(8)));
typedef float f32x4 __attribute__((ext_vector_type(4)));
typedef const __attribute__((address_space(1))) void* gptr_t;
typedef __attribute__((address_space(3))) void* lptr_t;

// LDS half-offsets
#define CBS_BASE 0       // sim B: 8 sub-images [128 kp][32 d],  sub = d>>5   (64 KB)
#define CBZ_BASE 32768   // z   B: 4 sub-images [256 d][32 kk],  sub = kk>>5  (64 KB)
#define PB_BASE  65536   // pbuf: per-wave 4 sub-images [16 row][32 kk]       (32 KB)

// ---------------------------------------------------------------------------
// Prep: per-prototype norm + scale; write both packed B-images into ws as one
// contiguous 128 KiB region (cbS then cbZ). grid: 128 blocks x 64 threads.
__global__ void k_prep(const float* __restrict__ proto,
                       float* __restrict__ scale,
                       _Float16* __restrict__ img) {
    const int kp = blockIdx.x;
    const int lane = threadIdx.x;
    const float4 v = ((const float4*)(proto + kp * 256))[lane];
    float s = v.x * v.x + v.y * v.y + v.z * v.z + v.w * v.w;
    #pragma unroll
    for (int msk = 1; msk < 64; msk <<= 1) s += __shfl_xor(s, msk, 64);
    const float sc = fmaxf(sqrtf(s), EPS);   // proto = cbar * sc exactly
    const float inv = 1.0f / sc;
    if (lane == 0) scale[kp] = sc;
    const int d0 = lane * 4;
    _Float16 c[4];
    c[0] = (_Float16)(v.x * inv); c[1] = (_Float16)(v.y * inv);
    c[2] = (_Float16)(v.z * inv); c[3] = (_Float16)(v.w * inv);
    // cbS[sub = d>>5][kp][d&31] : sub-image = 128*32 halves = 4096
    {
        const int sub = d0 >> 5, dl = d0 & 31;
        _Float16* p = img + sub * 4096 + kp * 32 + dl;
        #pragma unroll
        for (int i = 0; i < 4; i++) p[i] = c[i];
    }
    // cbZ[sub = kp>>5][d][kp&31] : sub-image = 256*32 halves = 8192
    // cbZ begins after cbS = 8*4096 = 32768 HALVES (64 KiB).
    {
        const int sub = kp >> 5, kl = kp & 31;
        _Float16* p = img + 32768 + sub * 8192 + kl;
        #pragma unroll
        for (int i = 0; i < 4; i++) p[(d0 + i) * 32] = c[i];
    }
}

// ---------------------------------------------------------------------------
// Main: 512 threads = 8 waves, 128 rows/block (16/wave), grid = M/128.
__global__ __launch_bounds__(512, 2) void k_main(
    const float* __restrict__ h,
    const float* __restrict__ scale,
    const char* __restrict__ img,          // 128 KiB packed cbS||cbZ
    float* __restrict__ out_p,
    float* __restrict__ out_z) {

    __shared__ __align__(16) _Float16 L[81920];   // 163840 B = full CU LDS

    const int tid = threadIdx.x;
    const int w = tid >> 6;         // wave 0..7
    const int lane = tid & 63;
    const int m = lane & 15;
    const int quad = lane >> 4;
    const int row0 = blockIdx.x * 128 + w * 16;

    // --- stage cbS (chunks 0..63, LDS offsets < 64 KiB) via async DMA
    #pragma unroll
    for (int it = 0; it < 8; ++it) {
        const int c = it * 8 + w;
        __builtin_amdgcn_global_load_lds((gptr_t)(img + c * 1024 + lane * 16),
                                         (lptr_t)((char*)L + c * 1024), 16, 0, 0);
    }

    // --- cbZ (chunks 64..127): plain loads into VGPRs (full-address ds_write later)
    f16x8 zc[8];
    #pragma unroll
    for (int it = 0; it < 8; ++it) {
        const int c = 64 + it * 8 + w;
        zc[it] = *(const f16x8*)(img + c * 1024 + lane * 16);
    }

    // --- h loads, A layout: lane = row m, d = c*32+quad*8+j
    const float* hrow = h + (size_t)(row0 + m) * 256 + quad * 8;
    float hv[64];
    #pragma unroll
    for (int c = 0; c < 8; c++) {
        const float4 a = *(const float4*)(hrow + c * 32);
        const float4 b = *(const float4*)(hrow + c * 32 + 4);
        hv[c*8+0]=a.x; hv[c*8+1]=a.y; hv[c*8+2]=a.z; hv[c*8+3]=a.w;
        hv[c*8+4]=b.x; hv[c*8+5]=b.y; hv[c*8+6]=b.z; hv[c*8+7]=b.w;
    }

    // --- write cbZ into LDS (contiguous 16B/lane -> conflict-free b128)
    #pragma unroll
    for (int it = 0; it < 8; ++it) {
        const int c = 64 + it * 8 + w;
        *(f16x8*)((char*)L + c * 1024 + lane * 16) = zc[it];
    }

    // --- row norm (lanes {m,m+16,m+32,m+48} hold quarters of row m)
    float s = 0.f;
    #pragma unroll
    for (int i = 0; i < 64; i++) s += hv[i] * hv[i];
    s += __shfl_xor(s, 16, 64);
    s += __shfl_xor(s, 32, 64);
    const float inv = 1.0f / fmaxf(sqrtf(s), EPS);

    f16x8 A[8];
    #pragma unroll
    for (int c = 0; c < 8; c++) {
        #pragma unroll
        for (int j = 0; j < 8; j++) A[c][j] = (_Float16)(hv[c*8+j] * inv);
    }

    __syncthreads();   // both images resident; ONLY barrier in the kernel

    // --- sim GEMM: acc[t] = rows x (kp = t*16+m'), reduce d = c*32+quad*8+j
    f32x4 acc[8] = {};
    #pragma unroll
    for (int t = 0; t < 8; t++) {
        #pragma unroll
        for (int c = 0; c < 8; c++) {
            const f16x8 B = *(const f16x8*)&L[CBS_BASE + c * 4096 + (t * 16 + m) * 32 + quad * 8];
            acc[t] = __builtin_amdgcn_mfma_f32_16x16x32_f16(A[c], B, acc[t], 0, 0, 0);
        }
    }

    // per-lane prototype scales for z (proto = cbar * scale)
    float sc_l[8];
    #pragma unroll
    for (int t = 0; t < 8; t++) sc_l[t] = scale[t * 16 + m];

    // --- softmax over K=128 per row (fp32, within 16-lane quad groups)
    const int pw = PB_BASE + w * 2048;   // wave-private pbuf (halves)
    #pragma unroll
    for (int r = 0; r < 4; r++) {
        float mx = acc[0][r];
        #pragma unroll
        for (int t = 1; t < 8; t++) mx = fmaxf(mx, acc[t][r]);
        #pragma unroll
        for (int msk = 1; msk < 16; msk <<= 1) mx = fmaxf(mx, __shfl_xor(mx, msk, 64));
        float e[8];
        float sum = 0.f;
        #pragma unroll
        for (int t = 0; t < 8; t++) {
            e[t] = __expf((acc[t][r] - mx) * TAU_INV);
            sum += e[t];
        }
        #pragma unroll
        for (int msk = 1; msk < 16; msk <<= 1) sum += __shfl_xor(sum, msk, 64);
        const float rs = 1.0f / sum;
        const int grow = row0 + quad * 4 + r;
        float* po = out_p + (size_t)grow * 128;
        #pragma unroll
        for (int t = 0; t < 8; t++) {
            const float p = e[t] * rs;
            po[t * 16 + m] = p;
            // pbuf[sub = kp>>5][row = quad*4+r][col = kp&31], kp = t*16+m
            L[pw + (t >> 1) * 512 + (quad * 4 + r) * 32 + (t & 1) * 16 + m] =
                (_Float16)(p * sc_l[t]);
        }
    }

    // --- z GEMM: A = p*scale from wave-private pbuf (same-wave RAW: lgkmcnt)
    f16x8 Ap[4];
    #pragma unroll
    for (int c2 = 0; c2 < 4; c2++)
        Ap[c2] = *(const f16x8*)&L[pw + c2 * 512 + m * 32 + quad * 8];

    #pragma unroll
    for (int dt = 0; dt < 16; dt++) {
        f32x4 az = {};
        #pragma unroll
        for (int c2 = 0; c2 < 4; c2++) {
            const f16x8 B = *(const f16x8*)&L[CBZ_BASE + c2 * 8192 + (dt * 16 + m) * 32 + quad * 8];
            az = __builtin_amdgcn_mfma_f32_16x16x32_f16(Ap[c2], B, az, 0, 0, 0);
        }
        #pragma unroll
        for (int r = 0; r < 4; r++)
            out_z[(size_t)(row0 + quad * 4 + r) * 256 + dt * 16 + m] = az[r];
    }
}

// ---------------------------------------------------------------------------
extern "C" void kernel_launch(void* const* d_in, const int* in_sizes, int n_in,
                              void* d_out, int out_size, void* d_ws, size_t ws_size,
                              hipStream_t stream) {
    const float* h_in  = (const float*)d_in[0];   // (B,P,D) fp32, B*P=65536, D=256
    const float* proto = (const float*)d_in[1];   // (K,D) fp32, K=128

    const int M = in_sizes[0] / 256;              // 65536 rows

    // ws: scale[128] f32 (1 KiB slot) | packed images cbS||cbZ (128 KiB)
    float* scale = (float*)d_ws;
    char*  img   = (char*)d_ws + 1024;

    float* out_p = (float*)d_out;                 // (M,128)
    float* out_z = out_p + (size_t)M * 128;       // (M,256)

    k_prep<<<dim3(128), dim3(64), 0, stream>>>(proto, scale, (_Float16*)img);
    k_main<<<dim3(M / 128), dim3(512), 0, stream>>>(h_in, scale, img, out_p, out_z);
}